// Round 2
// baseline (148946.460 us; speedup 1.0000x reference)
//
#include <hip/hip_runtime.h>
#include <stdint.h>

#define LAYERS 4
#define H2 2048
#define TT 2048
#define NPAIR 1024            // f16 pairs per h vector
#define NSLOT (TT + 1)        // time-slot indices 0..2048

typedef _Float16 half2v __attribute__((ext_vector_type(2)));

__device__ __forceinline__ float sigf(float x) { return 1.0f / (1.0f + __expf(-x)); }
__device__ __forceinline__ float tanhf_fast(float x) { return 1.0f - 2.0f / (__expf(2.0f * x) + 1.0f); }

// slots layout: u64 slots[4][2049][1024]; value = (tag<<32) | f16pair, tag = time-index (1..2048)
// slot[l][ti] holds h^l(t = ti-1). ti==0 (initial zeros) is never stored/read (special-cased).

__global__ void __launch_bounds__(1024) rnn_scan(
    const float* __restrict__ event,
    const float* __restrict__ w_ih0,
    const float* __restrict__ w_ih,
    const float* __restrict__ w_hh,
    const float* __restrict__ b_ih,
    const float* __restrict__ b_hh,
    unsigned long long* slots)
{
  const int layer = blockIdx.x >> 6;
  const int slice = blockIdx.x & 63;
  const int wave  = threadIdx.x >> 6;
  const int lane  = threadIdx.x & 63;
  const int PI    = (layer == 0) ? 4 : 8;   // 16B-chunks of pairs per row (layer0: 2048-dot, else 4096-dot)

  __shared__ __align__(16) unsigned lds_h[2][2048];  // [parity][pair]; [0:1024)=h_own, [1024:2048)=h_prev

  // ---- one-time: load this wave's 8 gate rows as packed f16 pairs into registers ----
  const float* whh_l = w_hh + (size_t)layer * 8192 * 2048;
  const float* wih_l = (layer > 0) ? (w_ih + (size_t)(layer - 1) * 8192 * 2048) : whh_l;

  unsigned wreg[256];
  float bsum[8], w0v[8];
#pragma unroll
  for (int m = 0; m < 8; ++m) {
    const int row = ((m & 3) << 11) + (slice << 5) + (wave << 1) + (m >> 2);
    const float* ph = whh_l + (size_t)row * H2;
    const float* pi = wih_l + (size_t)row * H2;
    bsum[m] = b_ih[layer * 8192 + row] + b_hh[layer * 8192 + row];
    w0v[m]  = (layer == 0) ? w_ih0[row] : 0.0f;
#pragma unroll
    for (int i = 0; i < 8; ++i) {
      float4 a, b;
      if (i < PI) {
        const float* p = (i < 4) ? (ph + i * 512 + lane * 8) : (pi + (i - 4) * 512 + lane * 8);
        a = *(const float4*)p;
        b = *(const float4*)(p + 4);
      } else {
        a = make_float4(0.f, 0.f, 0.f, 0.f);
        b = a;
      }
      wreg[(m << 5) + (i << 2) + 0] = __builtin_bit_cast(unsigned, __builtin_amdgcn_cvt_pkrtz(a.x, a.y));
      wreg[(m << 5) + (i << 2) + 1] = __builtin_bit_cast(unsigned, __builtin_amdgcn_cvt_pkrtz(a.z, a.w));
      wreg[(m << 5) + (i << 2) + 2] = __builtin_bit_cast(unsigned, __builtin_amdgcn_cvt_pkrtz(b.x, b.y));
      wreg[(m << 5) + (i << 2) + 3] = __builtin_bit_cast(unsigned, __builtin_amdgcn_cvt_pkrtz(b.z, b.w));
    }
  }

  float c0 = 0.f, c1 = 0.f;

  for (int r = 0; r < TT + LAYERS - 1; ++r) {
    const int t = r - layer;
    if ((unsigned)t >= (unsigned)TT) continue;   // block-uniform
    unsigned* buf = lds_h[r & 1];

    // ---- staging: wave0 -> h_own(t-1), wave1 -> h_prev-layer(t) ----
    if (wave == 0) {
      if (t == 0) {
#pragma unroll
        for (int i = 0; i < 16; ++i) buf[lane + (i << 6)] = 0u;
      } else {
        unsigned long long* sp = slots + ((size_t)layer * NSLOT + t) * NPAIR;
        const unsigned tag = (unsigned)t;
        unsigned long long v[16];
#pragma unroll
        for (int i = 0; i < 16; ++i)
          v[i] = __hip_atomic_load(&sp[lane + (i << 6)], __ATOMIC_RELAXED, __HIP_MEMORY_SCOPE_AGENT);
        bool bad = true;
        while (bad) {
          bad = false;
#pragma unroll
          for (int i = 0; i < 16; ++i) {
            if ((unsigned)(v[i] >> 32) != tag) {
              v[i] = __hip_atomic_load(&sp[lane + (i << 6)], __ATOMIC_RELAXED, __HIP_MEMORY_SCOPE_AGENT);
              bad = true;
            }
          }
        }
#pragma unroll
        for (int i = 0; i < 16; ++i) buf[lane + (i << 6)] = (unsigned)v[i];
      }
    } else if (wave == 1 && layer > 0) {
      unsigned long long* sp = slots + ((size_t)(layer - 1) * NSLOT + (t + 1)) * NPAIR;
      const unsigned tag = (unsigned)(t + 1);
      unsigned long long v[16];
#pragma unroll
      for (int i = 0; i < 16; ++i)
        v[i] = __hip_atomic_load(&sp[lane + (i << 6)], __ATOMIC_RELAXED, __HIP_MEMORY_SCOPE_AGENT);
      bool bad = true;
      while (bad) {
        bad = false;
#pragma unroll
        for (int i = 0; i < 16; ++i) {
          if ((unsigned)(v[i] >> 32) != tag) {
            v[i] = __hip_atomic_load(&sp[lane + (i << 6)], __ATOMIC_RELAXED, __HIP_MEMORY_SCOPE_AGENT);
            bad = true;
          }
        }
      }
#pragma unroll
      for (int i = 0; i < 16; ++i) buf[1024 + lane + (i << 6)] = (unsigned)v[i];
    }
    __syncthreads();

    // ---- per-wave: 8 gate rows, length-4096 (or 2048) dots with register weights ----
    unsigned hp[32];
#pragma unroll
    for (int i = 0; i < 8; ++i) {
      if (i < PI) {
        const uint4 u = *(const uint4*)&buf[(i << 8) + (lane << 2)];
        hp[(i << 2) + 0] = u.x; hp[(i << 2) + 1] = u.y;
        hp[(i << 2) + 2] = u.z; hp[(i << 2) + 3] = u.w;
      }
    }

    float acc[8];
#pragma unroll
    for (int m = 0; m < 8; ++m) {
      float a0 = 0.f, a1 = 0.f;
#pragma unroll
      for (int i = 0; i < 8; ++i) {
        if (i < PI) {
#pragma unroll
          for (int j = 0; j < 4; ++j) {
            const half2v wv = __builtin_bit_cast(half2v, wreg[(m << 5) + (i << 2) + j]);
            const half2v hv = __builtin_bit_cast(half2v, hp[(i << 2) + j]);
            if (j & 1) a1 = __builtin_amdgcn_fdot2(wv, hv, a1, false);
            else       a0 = __builtin_amdgcn_fdot2(wv, hv, a0, false);
          }
        }
      }
      acc[m] = a0 + a1;
    }

#pragma unroll
    for (int m = 0; m < 8; ++m) {
      float a = acc[m];
#pragma unroll
      for (int s = 1; s < 64; s <<= 1) a += __shfl_xor(a, s, 64);
      acc[m] = a;
    }

    // ---- finalize (redundant on all lanes; no divergence) ----
    const float ev = (layer == 0) ? event[t] : 0.0f;
    const float g0 = acc[0] + bsum[0] + ev * w0v[0];
    const float g1 = acc[1] + bsum[1] + ev * w0v[1];
    const float g2 = acc[2] + bsum[2] + ev * w0v[2];
    const float g3 = acc[3] + bsum[3] + ev * w0v[3];
    const float g4 = acc[4] + bsum[4] + ev * w0v[4];
    const float g5 = acc[5] + bsum[5] + ev * w0v[5];
    const float g6 = acc[6] + bsum[6] + ev * w0v[6];
    const float g7 = acc[7] + bsum[7] + ev * w0v[7];

    c0 = sigf(g1) * c0 + sigf(g0) * tanhf_fast(g2);
    const float h0 = sigf(g3) * tanhf_fast(c0);
    c1 = sigf(g5) * c1 + sigf(g4) * tanhf_fast(g6);
    const float h1 = sigf(g7) * tanhf_fast(c1);

    if (lane == 0) {
      const unsigned hbits = __builtin_bit_cast(unsigned, __builtin_amdgcn_cvt_pkrtz(h0, h1));
      const unsigned long long val =
          ((unsigned long long)(unsigned)(t + 1) << 32) | (unsigned long long)hbits;
      __hip_atomic_store(&slots[((size_t)layer * NSLOT + (t + 1)) * NPAIR + (slice << 4) + wave],
                         val, __ATOMIC_RELAXED, __HIP_MEMORY_SCOPE_AGENT);
    }
  }
}

__global__ void rnn_tail(const unsigned long long* __restrict__ slots,
                         const float* __restrict__ w_out,
                         const float* __restrict__ b_out,
                         float* __restrict__ out)
{
  __shared__ float red0[4], red1[4];
  const int tid = threadIdx.x;
  float s0 = 0.f, s1 = 0.f;
  const unsigned long long* hp = slots + ((size_t)3 * NSLOT + TT) * NPAIR;
  for (int q = tid; q < NPAIR; q += 256) {
    const unsigned pv = (unsigned)hp[q];
    const half2v h2 = __builtin_bit_cast(half2v, pv);
    const float ha = (float)h2.x, hb = (float)h2.y;
    s0 += ha * w_out[2 * q] + hb * w_out[2 * q + 1];
    s1 += ha * w_out[H2 + 2 * q] + hb * w_out[H2 + 2 * q + 1];
  }
#pragma unroll
  for (int s = 1; s < 64; s <<= 1) { s0 += __shfl_xor(s0, s, 64); s1 += __shfl_xor(s1, s, 64); }
  if ((tid & 63) == 0) { red0[tid >> 6] = s0; red1[tid >> 6] = s1; }
  __syncthreads();
  if (tid == 0) {
    const float l0 = red0[0] + red0[1] + red0[2] + red0[3] + b_out[0];
    const float l1 = red1[0] + red1[1] + red1[2] + red1[3] + b_out[1];
    const float mx = fmaxf(l0, l1);
    const float lse = mx + logf(__expf(l0 - mx) + __expf(l1 - mx));
    out[0] = l0 - lse;
    out[1] = l1 - lse;
  }
}

extern "C" void kernel_launch(void* const* d_in, const int* in_sizes, int n_in,
                              void* d_out, int out_size, void* d_ws, size_t ws_size,
                              hipStream_t stream)
{
  const float* event = (const float*)d_in[0];
  const float* w_ih0 = (const float*)d_in[1];
  const float* w_ih  = (const float*)d_in[2];
  const float* w_hh  = (const float*)d_in[3];
  const float* b_ih  = (const float*)d_in[4];
  const float* b_hh  = (const float*)d_in[5];
  const float* w_out = (const float*)d_in[6];
  const float* b_out = (const float*)d_in[7];
  unsigned long long* slots = (unsigned long long*)d_ws;   // needs 4*2049*1024*8 = 67.1 MB

  void* args[] = {(void*)&event, (void*)&w_ih0, (void*)&w_ih, (void*)&w_hh,
                  (void*)&b_ih, (void*)&b_hh, (void*)&slots};
  (void)hipLaunchCooperativeKernel((void*)rnn_scan, dim3(256), dim3(1024), args, 0, stream);

  hipLaunchKernelGGL(rnn_tail, dim3(1), dim3(256), 0, stream,
                     (const unsigned long long*)slots, w_out, b_out, (float*)d_out);
}